// Round 8
// baseline (284.732 us; speedup 1.0000x reference)
//
#include <hip/hip_runtime.h>

#define N_NODES 50000
#define N_EDGES 800000
#define SCAN_TILE 2048  // 256 threads x 8 elems
#define CNT_STRIDE 16   // one counter per 64B line (kills false sharing)

static_assert(N_NODES < 65536, "col must fit in 16 bits for packed CSR");

typedef __attribute__((ext_vector_type(4))) float f32x4;
typedef __attribute__((ext_vector_type(8))) short bf16x8;

__device__ inline unsigned short f32_to_bf16(float f) {
    unsigned int u = __builtin_bit_cast(unsigned int, f);
    u += 0x7FFF + ((u >> 16) & 1);  // RNE
    return (unsigned short)(u >> 16);
}
__device__ inline float bf16_to_f32(unsigned short h) {
    unsigned int u = ((unsigned int)h) << 16;
    return __builtin_bit_cast(float, u);
}

// ---------------------------------------------------------------------------
// Fused prep: x->bf16 (float4-wise), W1/W2/W3 -> transposed bf16, zero cnt.
// One dispatch; work segments selected by global index range.
// ---------------------------------------------------------------------------
#define XN4   ((long long)N_NODES * 128 / 4)   // 1,600,000
#define W128  (128 * 128)
#define W64   (128 * 64)
#define CNT4  (N_NODES * CNT_STRIDE / 4)       // 200,000

__global__ void prep(const float* __restrict__ x, unsigned short* __restrict__ Xb,
                     const float* __restrict__ W1, const float* __restrict__ W2,
                     const float* __restrict__ W3, unsigned short* __restrict__ Wt1,
                     unsigned short* __restrict__ Wt2, unsigned short* __restrict__ Wt3,
                     int* __restrict__ cnt) {
    long long gid = (long long)blockIdx.x * blockDim.x + threadIdx.x;
    if (gid < XN4) {
        float4 v = reinterpret_cast<const float4*>(x)[gid];
        ushort4 o;
        o.x = f32_to_bf16(v.x); o.y = f32_to_bf16(v.y);
        o.z = f32_to_bf16(v.z); o.w = f32_to_bf16(v.w);
        reinterpret_cast<ushort4*>(Xb)[gid] = o;
        return;
    }
    long long r = gid - XN4;
    if (r < W128) {
        int k = (int)r / 128, m = (int)r % 128;
        Wt1[m * 128 + k] = f32_to_bf16(W1[r]);
        return;
    }
    r -= W128;
    if (r < W128) {
        int k = (int)r / 128, m = (int)r % 128;
        Wt2[m * 128 + k] = f32_to_bf16(W2[r]);
        return;
    }
    r -= W128;
    if (r < W64) {
        int k = (int)r / 64, m = (int)r % 64;
        Wt3[m * 128 + k] = f32_to_bf16(W3[r]);
        return;
    }
    r -= W64;
    if (r < CNT4) {
        int4 z = {0, 0, 0, 0};
        reinterpret_cast<int4*>(cnt)[r] = z;
    }
}

// ---------------------------------------------------------------------------
// CSR build: rank histogram (one atomic pass, rank returned) -> multi-block
// scan -> atomic-free slot fill
// ---------------------------------------------------------------------------
__global__ void rank_histogram(const int* __restrict__ erow, int* __restrict__ cnt,
                               int* __restrict__ rank) {
    int e = blockIdx.x * blockDim.x + threadIdx.x;
    if (e < N_EDGES) rank[e] = atomicAdd(&cnt[(size_t)erow[e] * CNT_STRIDE], 1);
}

__global__ void scan_tiles(const int* __restrict__ cnt, int* __restrict__ local,
                           int* __restrict__ tsum, int n) {
    __shared__ int sums[256];
    const int t = threadIdx.x;
    const int base = blockIdx.x * SCAN_TILE + t * 8;
    int v[8];
    int s = 0;
#pragma unroll
    for (int i = 0; i < 8; ++i) {
        v[i] = (base + i < n) ? cnt[(size_t)(base + i) * CNT_STRIDE] : 0;
        s += v[i];
    }
    sums[t] = s;
    __syncthreads();
    for (int off = 1; off < 256; off <<= 1) {
        int x = (t >= off) ? sums[t - off] : 0;
        __syncthreads();
        sums[t] += x;
        __syncthreads();
    }
    int run = sums[t] - s;
#pragma unroll
    for (int i = 0; i < 8; ++i) {
        if (base + i < n) local[base + i] = run;
        run += v[i];
    }
    if (t == 255) tsum[blockIdx.x] = run;
}

__global__ void scan_finalize(const int* __restrict__ local,
                              const int* __restrict__ tsum, int ntiles,
                              int* __restrict__ rptr, int n) {
    __shared__ int off_s;
    const int b = blockIdx.x;
    if (threadIdx.x == 0) {
        int s = 0;
        for (int i = 0; i < b; ++i) s += tsum[i];
        off_s = s;
        if (b == 0) {
            int tot = 0;
            for (int i = 0; i < ntiles; ++i) tot += tsum[i];
            rptr[n] = tot;
        }
    }
    __syncthreads();
    const int off = off_s;
    const int base = b * SCAN_TILE + threadIdx.x * 8;
#pragma unroll
    for (int i = 0; i < 8; ++i) {
        int idx = base + i;
        if (idx < n) rptr[idx] = local[idx] + off;
    }
}

__global__ void fill_csr(const int* __restrict__ erow, const int* __restrict__ ecol,
                         const float* __restrict__ eval, const int* __restrict__ rptr,
                         const int* __restrict__ rank,
                         unsigned int* __restrict__ cpack) {
    int e = blockIdx.x * blockDim.x + threadIdx.x;
    if (e >= N_EDGES) return;
    int slot = rptr[erow[e]] + rank[e];
    unsigned int p = (unsigned int)(ecol[e] & 0xFFFF) |
                     ((unsigned int)f32_to_bf16(eval[e]) << 16);
    cpack[slot] = p;
}

// ---------------------------------------------------------------------------
// MFMA GEMM (persistent-W, grid-stride over 64-row tiles):
// Y[N,NOUT] = Xb[N,128](bf16) @ W (staged transposed, bf16)
// Fragment layouts [measured m89/m91/m120].
// ---------------------------------------------------------------------------
template <int NOUT, bool OUT_BF16>
__global__ __launch_bounds__(256) void gemm_mfma(
    const unsigned short* __restrict__ Xb, const unsigned short* __restrict__ Wt,
    void* __restrict__ Yv, int N, int ntiles) {
    constexpr int K = 128;
    constexpr int KP = K + 8;
    constexpr int NT = NOUT / 16;
    __shared__ unsigned short Xs[64 * KP];
    __shared__ unsigned short Ws[NOUT * KP];

    const int tid = threadIdx.x;
    const int wave = tid >> 6;
    const int lane = tid & 63;
    const int m = lane & 15;
    const int quad = lane >> 4;
    const int rowbase = wave * 16;

    for (int idx = tid; idx < NOUT * 16; idx += 256) {
        int r = idx >> 4, ch = idx & 15;
        uint4 v = *reinterpret_cast<const uint4*>(Wt + r * K + ch * 8);
        *reinterpret_cast<uint4*>(Ws + r * KP + ch * 8) = v;
    }

    for (int tile = blockIdx.x; tile < ntiles; tile += gridDim.x) {
        const int block_row = tile * 64;
        for (int idx = tid; idx < 64 * 16; idx += 256) {
            int r = idx >> 4, ch = idx & 15;
            int gr = block_row + r;
            if (gr >= N) gr = N - 1;
            uint4 v = *reinterpret_cast<const uint4*>(Xb + (size_t)gr * K + ch * 8);
            *reinterpret_cast<uint4*>(Xs + r * KP + ch * 8) = v;
        }
        __syncthreads();

        f32x4 acc[NT];
#pragma unroll
        for (int t = 0; t < NT; ++t) acc[t] = (f32x4){0.f, 0.f, 0.f, 0.f};

#pragma unroll
        for (int kt = 0; kt < 4; ++kt) {
            bf16x8 a = *reinterpret_cast<const bf16x8*>(
                Xs + (rowbase + m) * KP + kt * 32 + quad * 8);
#pragma unroll
            for (int t = 0; t < NT; ++t) {
                bf16x8 b = *reinterpret_cast<const bf16x8*>(
                    Ws + (t * 16 + m) * KP + kt * 32 + quad * 8);
                acc[t] = __builtin_amdgcn_mfma_f32_16x16x32_bf16(a, b, acc[t], 0, 0, 0);
            }
        }
        __syncthreads();

#pragma unroll
        for (int t = 0; t < NT; ++t) {
#pragma unroll
            for (int r = 0; r < 4; ++r) {
                int grow = block_row + rowbase + quad * 4 + r;
                if (grow < N) {
                    if (OUT_BF16)
                        reinterpret_cast<unsigned short*>(Yv)[(size_t)grow * NOUT + t * 16 + m] =
                            f32_to_bf16(acc[t][r]);
                    else
                        reinterpret_cast<float*>(Yv)[(size_t)grow * NOUT + t * 16 + m] = acc[t][r];
                }
            }
        }
    }
}

// ---------------------------------------------------------------------------
// CSR aggregation, bf16 source [N,128], fused bias+ReLU, bf16 out.
// 32 lanes/node: two 16-lane sub-groups split edges by parity (halved gather
// chain, doubled MLP), butterfly-combined via __shfl_xor(.,16).
// ---------------------------------------------------------------------------
__global__ void aggregate_bf16(const unsigned short* __restrict__ S,
                               const int* __restrict__ rptr,
                               const unsigned int* __restrict__ cpack,
                               const float* __restrict__ bias,
                               unsigned short* __restrict__ outb, int N) {
    const int tid = threadIdx.x;
    const int node = blockIdx.x * (blockDim.x / 32) + tid / 32;
    const int sub = (tid >> 4) & 1;
    const int f8 = tid & 15;
    if (node >= N) return;
    const int beg = rptr[node];
    const int end = rptr[node + 1];
    float acc[8];
#pragma unroll
    for (int i = 0; i < 8; ++i) acc[i] = sub ? 0.0f : bias[f8 * 8 + i];
    int j = beg + sub;
    for (; j + 6 < end; j += 8) {  // j, j+2, j+4, j+6
        unsigned int p0 = cpack[j], p1 = cpack[j + 2];
        unsigned int p2 = cpack[j + 4], p3 = cpack[j + 6];
        uint4 s0 = *reinterpret_cast<const uint4*>(S + (size_t)(p0 & 0xFFFF) * 128 + f8 * 8);
        uint4 s1 = *reinterpret_cast<const uint4*>(S + (size_t)(p1 & 0xFFFF) * 128 + f8 * 8);
        uint4 s2 = *reinterpret_cast<const uint4*>(S + (size_t)(p2 & 0xFFFF) * 128 + f8 * 8);
        uint4 s3 = *reinterpret_cast<const uint4*>(S + (size_t)(p3 & 0xFFFF) * 128 + f8 * 8);
        const float v0 = bf16_to_f32((unsigned short)(p0 >> 16));
        const float v1 = bf16_to_f32((unsigned short)(p1 >> 16));
        const float v2 = bf16_to_f32((unsigned short)(p2 >> 16));
        const float v3 = bf16_to_f32((unsigned short)(p3 >> 16));
        const unsigned short* sp0 = reinterpret_cast<const unsigned short*>(&s0);
        const unsigned short* sp1 = reinterpret_cast<const unsigned short*>(&s1);
        const unsigned short* sp2 = reinterpret_cast<const unsigned short*>(&s2);
        const unsigned short* sp3 = reinterpret_cast<const unsigned short*>(&s3);
#pragma unroll
        for (int i = 0; i < 8; ++i) acc[i] = fmaf(v0, bf16_to_f32(sp0[i]), acc[i]);
#pragma unroll
        for (int i = 0; i < 8; ++i) acc[i] = fmaf(v1, bf16_to_f32(sp1[i]), acc[i]);
#pragma unroll
        for (int i = 0; i < 8; ++i) acc[i] = fmaf(v2, bf16_to_f32(sp2[i]), acc[i]);
#pragma unroll
        for (int i = 0; i < 8; ++i) acc[i] = fmaf(v3, bf16_to_f32(sp3[i]), acc[i]);
    }
    for (; j < end; j += 2) {
        unsigned int p = cpack[j];
        uint4 s = *reinterpret_cast<const uint4*>(S + (size_t)(p & 0xFFFF) * 128 + f8 * 8);
        const float v = bf16_to_f32((unsigned short)(p >> 16));
        const unsigned short* sp = reinterpret_cast<const unsigned short*>(&s);
#pragma unroll
        for (int i = 0; i < 8; ++i) acc[i] = fmaf(v, bf16_to_f32(sp[i]), acc[i]);
    }
    // combine sub-group partials (lanes l <-> l^16 within the 32-lane group)
#pragma unroll
    for (int i = 0; i < 8; ++i) acc[i] += __shfl_xor(acc[i], 16, 64);
    if (sub == 0) {
        unsigned short o[8];
#pragma unroll
        for (int i = 0; i < 8; ++i) o[i] = f32_to_bf16(fmaxf(acc[i], 0.0f));
        *reinterpret_cast<uint4*>(outb + (size_t)node * 128 + f8 * 8) =
            *reinterpret_cast<uint4*>(o);
    }
}

// ---------------------------------------------------------------------------
// Layer-3 aggregation: bf16 source [N,64], + bias, no activation, fp32 out.
// Same 32-lanes/node parity-split structure.
// ---------------------------------------------------------------------------
__global__ void aggregate_bf16_64(const unsigned short* __restrict__ S,
                                  const int* __restrict__ rptr,
                                  const unsigned int* __restrict__ cpack,
                                  const float* __restrict__ bias,
                                  float* __restrict__ out, int N) {
    const int tid = threadIdx.x;
    const int node = blockIdx.x * (blockDim.x / 32) + tid / 32;
    const int sub = (tid >> 4) & 1;
    const int f4 = tid & 15;
    if (node >= N) return;
    const int beg = rptr[node];
    const int end = rptr[node + 1];
    float acc[4];
#pragma unroll
    for (int i = 0; i < 4; ++i) acc[i] = sub ? 0.0f : bias[f4 * 4 + i];
    int j = beg + sub;
    for (; j + 6 < end; j += 8) {
        unsigned int p0 = cpack[j], p1 = cpack[j + 2];
        unsigned int p2 = cpack[j + 4], p3 = cpack[j + 6];
        uint2 s0 = *reinterpret_cast<const uint2*>(S + (size_t)(p0 & 0xFFFF) * 64 + f4 * 4);
        uint2 s1 = *reinterpret_cast<const uint2*>(S + (size_t)(p1 & 0xFFFF) * 64 + f4 * 4);
        uint2 s2 = *reinterpret_cast<const uint2*>(S + (size_t)(p2 & 0xFFFF) * 64 + f4 * 4);
        uint2 s3 = *reinterpret_cast<const uint2*>(S + (size_t)(p3 & 0xFFFF) * 64 + f4 * 4);
        const float v0 = bf16_to_f32((unsigned short)(p0 >> 16));
        const float v1 = bf16_to_f32((unsigned short)(p1 >> 16));
        const float v2 = bf16_to_f32((unsigned short)(p2 >> 16));
        const float v3 = bf16_to_f32((unsigned short)(p3 >> 16));
        const unsigned short* sp0 = reinterpret_cast<const unsigned short*>(&s0);
        const unsigned short* sp1 = reinterpret_cast<const unsigned short*>(&s1);
        const unsigned short* sp2 = reinterpret_cast<const unsigned short*>(&s2);
        const unsigned short* sp3 = reinterpret_cast<const unsigned short*>(&s3);
#pragma unroll
        for (int i = 0; i < 4; ++i) acc[i] = fmaf(v0, bf16_to_f32(sp0[i]), acc[i]);
#pragma unroll
        for (int i = 0; i < 4; ++i) acc[i] = fmaf(v1, bf16_to_f32(sp1[i]), acc[i]);
#pragma unroll
        for (int i = 0; i < 4; ++i) acc[i] = fmaf(v2, bf16_to_f32(sp2[i]), acc[i]);
#pragma unroll
        for (int i = 0; i < 4; ++i) acc[i] = fmaf(v3, bf16_to_f32(sp3[i]), acc[i]);
    }
    for (; j < end; j += 2) {
        unsigned int p = cpack[j];
        uint2 s = *reinterpret_cast<const uint2*>(S + (size_t)(p & 0xFFFF) * 64 + f4 * 4);
        const float v = bf16_to_f32((unsigned short)(p >> 16));
        const unsigned short* sp = reinterpret_cast<const unsigned short*>(&s);
#pragma unroll
        for (int i = 0; i < 4; ++i) acc[i] = fmaf(v, bf16_to_f32(sp[i]), acc[i]);
    }
#pragma unroll
    for (int i = 0; i < 4; ++i) acc[i] += __shfl_xor(acc[i], 16, 64);
    if (sub == 0) {
        float4 o = {acc[0], acc[1], acc[2], acc[3]};
        *reinterpret_cast<float4*>(out + (size_t)node * 64 + f4 * 4) = o;
    }
}

extern "C" void kernel_launch(void* const* d_in, const int* in_sizes, int n_in,
                              void* d_out, int out_size, void* d_ws, size_t ws_size,
                              hipStream_t stream) {
    const float* x    = (const float*)d_in[0];
    const int*   erow = (const int*)d_in[1];
    const int*   ecol = (const int*)d_in[2];
    const float* eval = (const float*)d_in[3];
    const float* W1   = (const float*)d_in[4];
    const float* b1   = (const float*)d_in[5];
    const float* W2   = (const float*)d_in[6];
    const float* b2   = (const float*)d_in[7];
    const float* W3   = (const float*)d_in[8];
    const float* b3   = (const float*)d_in[9];
    float* out = (float*)d_out;

    const size_t nf = (size_t)N_NODES * 128;
    unsigned short* Xb  = (unsigned short*)d_ws;
    unsigned short* Ab  = Xb + nf;
    unsigned short* Wt1 = Ab + nf;
    unsigned short* Wt2 = Wt1 + 128 * 128;
    unsigned short* Wt3 = Wt2 + 128 * 128;
    int*   cnt    = (int*)(Wt3 + 64 * 128);              // N_NODES * CNT_STRIDE
    int*   rank   = cnt + (size_t)N_NODES * CNT_STRIDE;  // N_EDGES
    int*   rptr   = rank + N_EDGES;                      // N_NODES + 1
    unsigned int* cpack = (unsigned int*)(rptr + N_NODES + 1);  // N_EDGES
    int*   slocal = (int*)(cpack + N_EDGES);             // N_NODES
    int*   stsum  = slocal + N_NODES;                    // tiles

    const int blk = 256;
    const int ntiles_g = (N_NODES + 63) / 64;
    const int gemm_grid = 256;
    const int agg_grid = (int)(((long long)N_NODES * 32 + blk - 1) / blk);
    const int ntiles = (N_NODES + SCAN_TILE - 1) / SCAN_TILE;

    // ---- fused prep (x->bf16, W transposes, cnt zero)
    {
        long long total = XN4 + W128 + W128 + W64 + CNT4;
        prep<<<(int)((total + blk - 1) / blk), blk, 0, stream>>>(
            x, Xb, W1, W2, W3, Wt1, Wt2, Wt3, cnt);
    }
    rank_histogram<<<(N_EDGES + blk - 1) / blk, blk, 0, stream>>>(erow, cnt, rank);
    scan_tiles<<<ntiles, 256, 0, stream>>>(cnt, slocal, stsum, N_NODES);
    scan_finalize<<<ntiles, 256, 0, stream>>>(slocal, stsum, ntiles, rptr, N_NODES);
    fill_csr<<<(N_EDGES + blk - 1) / blk, blk, 0, stream>>>(erow, ecol, eval, rptr,
                                                            rank, cpack);

    // ---- Layer 1
    gemm_mfma<128, true><<<gemm_grid, 256, 0, stream>>>(Xb, Wt1, Ab, N_NODES, ntiles_g);
    aggregate_bf16<<<agg_grid, blk, 0, stream>>>(Ab, rptr, cpack, b1, Xb, N_NODES);

    // ---- Layer 2
    gemm_mfma<128, true><<<gemm_grid, 256, 0, stream>>>(Xb, Wt2, Ab, N_NODES, ntiles_g);
    aggregate_bf16<<<agg_grid, blk, 0, stream>>>(Ab, rptr, cpack, b2, Xb, N_NODES);

    // ---- Layer 3 (bf16 support, fp32 accumulate + fp32 out)
    gemm_mfma<64, true><<<gemm_grid, 256, 0, stream>>>(Xb, Wt3, Ab, N_NODES, ntiles_g);
    aggregate_bf16_64<<<agg_grid, blk, 0, stream>>>(Ab, rptr, cpack, b3, out, N_NODES);
}

// Round 9
// 271.376 us; speedup vs baseline: 1.0492x; 1.0492x over previous
//
#include <hip/hip_runtime.h>

#define N_NODES 50000
#define N_EDGES 800000
#define SCAN_TILE 2048  // 256 threads x 8 elems
#define CNT_STRIDE 16   // one counter per 64B line (kills false sharing)

static_assert(N_NODES < 65536, "col must fit in 16 bits for packed CSR");

typedef __attribute__((ext_vector_type(4))) float f32x4;
typedef __attribute__((ext_vector_type(8))) short bf16x8;

__device__ inline unsigned short f32_to_bf16(float f) {
    unsigned int u = __builtin_bit_cast(unsigned int, f);
    u += 0x7FFF + ((u >> 16) & 1);  // RNE
    return (unsigned short)(u >> 16);
}
__device__ inline float bf16_to_f32(unsigned short h) {
    unsigned int u = ((unsigned int)h) << 16;
    return __builtin_bit_cast(float, u);
}

// ---------------------------------------------------------------------------
// Fused prep: x->bf16 (float4-wise), W1/W2/W3 -> transposed bf16, zero cnt.
// ---------------------------------------------------------------------------
#define XN4   ((long long)N_NODES * 128 / 4)   // 1,600,000
#define W128  (128 * 128)
#define W64   (128 * 64)
#define CNT4  (N_NODES * CNT_STRIDE / 4)       // 200,000

__global__ void prep(const float* __restrict__ x, unsigned short* __restrict__ Xb,
                     const float* __restrict__ W1, const float* __restrict__ W2,
                     const float* __restrict__ W3, unsigned short* __restrict__ Wt1,
                     unsigned short* __restrict__ Wt2, unsigned short* __restrict__ Wt3,
                     int* __restrict__ cnt) {
    long long gid = (long long)blockIdx.x * blockDim.x + threadIdx.x;
    if (gid < XN4) {
        float4 v = reinterpret_cast<const float4*>(x)[gid];
        ushort4 o;
        o.x = f32_to_bf16(v.x); o.y = f32_to_bf16(v.y);
        o.z = f32_to_bf16(v.z); o.w = f32_to_bf16(v.w);
        reinterpret_cast<ushort4*>(Xb)[gid] = o;
        return;
    }
    long long r = gid - XN4;
    if (r < W128) {
        int k = (int)r / 128, m = (int)r % 128;
        Wt1[m * 128 + k] = f32_to_bf16(W1[r]);
        return;
    }
    r -= W128;
    if (r < W128) {
        int k = (int)r / 128, m = (int)r % 128;
        Wt2[m * 128 + k] = f32_to_bf16(W2[r]);
        return;
    }
    r -= W128;
    if (r < W64) {
        int k = (int)r / 64, m = (int)r % 64;
        Wt3[m * 128 + k] = f32_to_bf16(W3[r]);
        return;
    }
    r -= W64;
    if (r < CNT4) {
        int4 z = {0, 0, 0, 0};
        reinterpret_cast<int4*>(cnt)[r] = z;
    }
}

// ---------------------------------------------------------------------------
// CSR build: rank histogram (one atomic pass, rank returned) -> multi-block
// scan -> atomic-free slot fill
// ---------------------------------------------------------------------------
__global__ void rank_histogram(const int* __restrict__ erow, int* __restrict__ cnt,
                               int* __restrict__ rank) {
    int e = blockIdx.x * blockDim.x + threadIdx.x;
    if (e < N_EDGES) rank[e] = atomicAdd(&cnt[(size_t)erow[e] * CNT_STRIDE], 1);
}

__global__ void scan_tiles(const int* __restrict__ cnt, int* __restrict__ local,
                           int* __restrict__ tsum, int n) {
    __shared__ int sums[256];
    const int t = threadIdx.x;
    const int base = blockIdx.x * SCAN_TILE + t * 8;
    int v[8];
    int s = 0;
#pragma unroll
    for (int i = 0; i < 8; ++i) {
        v[i] = (base + i < n) ? cnt[(size_t)(base + i) * CNT_STRIDE] : 0;
        s += v[i];
    }
    sums[t] = s;
    __syncthreads();
    for (int off = 1; off < 256; off <<= 1) {
        int x = (t >= off) ? sums[t - off] : 0;
        __syncthreads();
        sums[t] += x;
        __syncthreads();
    }
    int run = sums[t] - s;
#pragma unroll
    for (int i = 0; i < 8; ++i) {
        if (base + i < n) local[base + i] = run;
        run += v[i];
    }
    if (t == 255) tsum[blockIdx.x] = run;
}

__global__ void scan_finalize(const int* __restrict__ local,
                              const int* __restrict__ tsum, int ntiles,
                              int* __restrict__ rptr, int n) {
    __shared__ int off_s;
    const int b = blockIdx.x;
    if (threadIdx.x == 0) {
        int s = 0;
        for (int i = 0; i < b; ++i) s += tsum[i];
        off_s = s;
        if (b == 0) {
            int tot = 0;
            for (int i = 0; i < ntiles; ++i) tot += tsum[i];
            rptr[n] = tot;
        }
    }
    __syncthreads();
    const int off = off_s;
    const int base = b * SCAN_TILE + threadIdx.x * 8;
#pragma unroll
    for (int i = 0; i < 8; ++i) {
        int idx = base + i;
        if (idx < n) rptr[idx] = local[idx] + off;
    }
}

__global__ void fill_csr(const int* __restrict__ erow, const int* __restrict__ ecol,
                         const float* __restrict__ eval, const int* __restrict__ rptr,
                         const int* __restrict__ rank,
                         unsigned int* __restrict__ cpack) {
    int e = blockIdx.x * blockDim.x + threadIdx.x;
    if (e >= N_EDGES) return;
    int slot = rptr[erow[e]] + rank[e];
    unsigned int p = (unsigned int)(ecol[e] & 0xFFFF) |
                     ((unsigned int)f32_to_bf16(eval[e]) << 16);
    cpack[slot] = p;
}

// ---------------------------------------------------------------------------
// MFMA GEMM (persistent-W, grid-stride over 64-row tiles):
// Y[N,NOUT] = Xb[N,128](bf16) @ W (staged transposed, bf16)
// Fragment layouts [measured m89/m91/m120].
// ---------------------------------------------------------------------------
template <int NOUT, bool OUT_BF16>
__global__ __launch_bounds__(256) void gemm_mfma(
    const unsigned short* __restrict__ Xb, const unsigned short* __restrict__ Wt,
    void* __restrict__ Yv, int N, int ntiles) {
    constexpr int K = 128;
    constexpr int KP = K + 8;
    constexpr int NT = NOUT / 16;
    __shared__ unsigned short Xs[64 * KP];
    __shared__ unsigned short Ws[NOUT * KP];

    const int tid = threadIdx.x;
    const int wave = tid >> 6;
    const int lane = tid & 63;
    const int m = lane & 15;
    const int quad = lane >> 4;
    const int rowbase = wave * 16;

    for (int idx = tid; idx < NOUT * 16; idx += 256) {
        int r = idx >> 4, ch = idx & 15;
        uint4 v = *reinterpret_cast<const uint4*>(Wt + r * K + ch * 8);
        *reinterpret_cast<uint4*>(Ws + r * KP + ch * 8) = v;
    }

    for (int tile = blockIdx.x; tile < ntiles; tile += gridDim.x) {
        const int block_row = tile * 64;
        for (int idx = tid; idx < 64 * 16; idx += 256) {
            int r = idx >> 4, ch = idx & 15;
            int gr = block_row + r;
            if (gr >= N) gr = N - 1;
            uint4 v = *reinterpret_cast<const uint4*>(Xb + (size_t)gr * K + ch * 8);
            *reinterpret_cast<uint4*>(Xs + r * KP + ch * 8) = v;
        }
        __syncthreads();

        f32x4 acc[NT];
#pragma unroll
        for (int t = 0; t < NT; ++t) acc[t] = (f32x4){0.f, 0.f, 0.f, 0.f};

#pragma unroll
        for (int kt = 0; kt < 4; ++kt) {
            bf16x8 a = *reinterpret_cast<const bf16x8*>(
                Xs + (rowbase + m) * KP + kt * 32 + quad * 8);
#pragma unroll
            for (int t = 0; t < NT; ++t) {
                bf16x8 b = *reinterpret_cast<const bf16x8*>(
                    Ws + (t * 16 + m) * KP + kt * 32 + quad * 8);
                acc[t] = __builtin_amdgcn_mfma_f32_16x16x32_bf16(a, b, acc[t], 0, 0, 0);
            }
        }
        __syncthreads();

#pragma unroll
        for (int t = 0; t < NT; ++t) {
#pragma unroll
            for (int r = 0; r < 4; ++r) {
                int grow = block_row + rowbase + quad * 4 + r;
                if (grow < N) {
                    if (OUT_BF16)
                        reinterpret_cast<unsigned short*>(Yv)[(size_t)grow * NOUT + t * 16 + m] =
                            f32_to_bf16(acc[t][r]);
                    else
                        reinterpret_cast<float*>(Yv)[(size_t)grow * NOUT + t * 16 + m] = acc[t][r];
                }
            }
        }
    }
}

// ---------------------------------------------------------------------------
// CSR aggregation, bf16 source [N,128], fused bias+ReLU, bf16 out.
// 16 lanes/node, 8 features/lane. Tiered unroll 8/4/2/1: up to 8 gathers in
// flight, bounded serial tail (deg~16 -> usually two unroll-8 iterations).
// ---------------------------------------------------------------------------
__global__ void aggregate_bf16(const unsigned short* __restrict__ S,
                               const int* __restrict__ rptr,
                               const unsigned int* __restrict__ cpack,
                               const float* __restrict__ bias,
                               unsigned short* __restrict__ outb, int N) {
    const int node = blockIdx.x * (blockDim.x / 16) + threadIdx.x / 16;
    const int f8 = threadIdx.x & 15;
    if (node >= N) return;
    const int beg = rptr[node];
    const int end = rptr[node + 1];
    float acc[8];
#pragma unroll
    for (int i = 0; i < 8; ++i) acc[i] = bias[f8 * 8 + i];
    int j = beg;
    for (; j + 8 <= end; j += 8) {
        unsigned int p[8];
        uint4 s[8];
#pragma unroll
        for (int u = 0; u < 8; ++u) p[u] = cpack[j + u];
#pragma unroll
        for (int u = 0; u < 8; ++u)
            s[u] = *reinterpret_cast<const uint4*>(S + (size_t)(p[u] & 0xFFFF) * 128 + f8 * 8);
#pragma unroll
        for (int u = 0; u < 8; ++u) {
            const float v = bf16_to_f32((unsigned short)(p[u] >> 16));
            const unsigned short* sp = reinterpret_cast<const unsigned short*>(&s[u]);
#pragma unroll
            for (int i = 0; i < 8; ++i) acc[i] = fmaf(v, bf16_to_f32(sp[i]), acc[i]);
        }
    }
    if (j + 4 <= end) {
        unsigned int p[4];
        uint4 s[4];
#pragma unroll
        for (int u = 0; u < 4; ++u) p[u] = cpack[j + u];
#pragma unroll
        for (int u = 0; u < 4; ++u)
            s[u] = *reinterpret_cast<const uint4*>(S + (size_t)(p[u] & 0xFFFF) * 128 + f8 * 8);
#pragma unroll
        for (int u = 0; u < 4; ++u) {
            const float v = bf16_to_f32((unsigned short)(p[u] >> 16));
            const unsigned short* sp = reinterpret_cast<const unsigned short*>(&s[u]);
#pragma unroll
            for (int i = 0; i < 8; ++i) acc[i] = fmaf(v, bf16_to_f32(sp[i]), acc[i]);
        }
        j += 4;
    }
    if (j + 2 <= end) {
        unsigned int p[2];
        uint4 s[2];
#pragma unroll
        for (int u = 0; u < 2; ++u) p[u] = cpack[j + u];
#pragma unroll
        for (int u = 0; u < 2; ++u)
            s[u] = *reinterpret_cast<const uint4*>(S + (size_t)(p[u] & 0xFFFF) * 128 + f8 * 8);
#pragma unroll
        for (int u = 0; u < 2; ++u) {
            const float v = bf16_to_f32((unsigned short)(p[u] >> 16));
            const unsigned short* sp = reinterpret_cast<const unsigned short*>(&s[u]);
#pragma unroll
            for (int i = 0; i < 8; ++i) acc[i] = fmaf(v, bf16_to_f32(sp[i]), acc[i]);
        }
        j += 2;
    }
    if (j < end) {
        unsigned int p = cpack[j];
        uint4 s = *reinterpret_cast<const uint4*>(S + (size_t)(p & 0xFFFF) * 128 + f8 * 8);
        const float v = bf16_to_f32((unsigned short)(p >> 16));
        const unsigned short* sp = reinterpret_cast<const unsigned short*>(&s);
#pragma unroll
        for (int i = 0; i < 8; ++i) acc[i] = fmaf(v, bf16_to_f32(sp[i]), acc[i]);
    }
    unsigned short o[8];
#pragma unroll
    for (int i = 0; i < 8; ++i) o[i] = f32_to_bf16(fmaxf(acc[i], 0.0f));
    *reinterpret_cast<uint4*>(outb + (size_t)node * 128 + f8 * 8) =
        *reinterpret_cast<uint4*>(o);
}

// ---------------------------------------------------------------------------
// Layer-3 aggregation: bf16 source [N,64], + bias, no activation, fp32 out.
// 16 lanes/node, 4 features/lane (uint2). Same tiered unroll 8/4/2/1.
// ---------------------------------------------------------------------------
__global__ void aggregate_bf16_64(const unsigned short* __restrict__ S,
                                  const int* __restrict__ rptr,
                                  const unsigned int* __restrict__ cpack,
                                  const float* __restrict__ bias,
                                  float* __restrict__ out, int N) {
    const int node = blockIdx.x * (blockDim.x / 16) + threadIdx.x / 16;
    const int f4 = threadIdx.x & 15;
    if (node >= N) return;
    const int beg = rptr[node];
    const int end = rptr[node + 1];
    float acc[4];
#pragma unroll
    for (int i = 0; i < 4; ++i) acc[i] = bias[f4 * 4 + i];
    int j = beg;
    for (; j + 8 <= end; j += 8) {
        unsigned int p[8];
        uint2 s[8];
#pragma unroll
        for (int u = 0; u < 8; ++u) p[u] = cpack[j + u];
#pragma unroll
        for (int u = 0; u < 8; ++u)
            s[u] = *reinterpret_cast<const uint2*>(S + (size_t)(p[u] & 0xFFFF) * 64 + f4 * 4);
#pragma unroll
        for (int u = 0; u < 8; ++u) {
            const float v = bf16_to_f32((unsigned short)(p[u] >> 16));
            const unsigned short* sp = reinterpret_cast<const unsigned short*>(&s[u]);
#pragma unroll
            for (int i = 0; i < 4; ++i) acc[i] = fmaf(v, bf16_to_f32(sp[i]), acc[i]);
        }
    }
    if (j + 4 <= end) {
        unsigned int p[4];
        uint2 s[4];
#pragma unroll
        for (int u = 0; u < 4; ++u) p[u] = cpack[j + u];
#pragma unroll
        for (int u = 0; u < 4; ++u)
            s[u] = *reinterpret_cast<const uint2*>(S + (size_t)(p[u] & 0xFFFF) * 64 + f4 * 4);
#pragma unroll
        for (int u = 0; u < 4; ++u) {
            const float v = bf16_to_f32((unsigned short)(p[u] >> 16));
            const unsigned short* sp = reinterpret_cast<const unsigned short*>(&s[u]);
#pragma unroll
            for (int i = 0; i < 4; ++i) acc[i] = fmaf(v, bf16_to_f32(sp[i]), acc[i]);
        }
        j += 4;
    }
    if (j + 2 <= end) {
        unsigned int p[2];
        uint2 s[2];
#pragma unroll
        for (int u = 0; u < 2; ++u) p[u] = cpack[j + u];
#pragma unroll
        for (int u = 0; u < 2; ++u)
            s[u] = *reinterpret_cast<const uint2*>(S + (size_t)(p[u] & 0xFFFF) * 64 + f4 * 4);
#pragma unroll
        for (int u = 0; u < 2; ++u) {
            const float v = bf16_to_f32((unsigned short)(p[u] >> 16));
            const unsigned short* sp = reinterpret_cast<const unsigned short*>(&s[u]);
#pragma unroll
            for (int i = 0; i < 4; ++i) acc[i] = fmaf(v, bf16_to_f32(sp[i]), acc[i]);
        }
        j += 2;
    }
    if (j < end) {
        unsigned int p = cpack[j];
        uint2 s = *reinterpret_cast<const uint2*>(S + (size_t)(p & 0xFFFF) * 64 + f4 * 4);
        const float v = bf16_to_f32((unsigned short)(p >> 16));
        const unsigned short* sp = reinterpret_cast<const unsigned short*>(&s);
#pragma unroll
        for (int i = 0; i < 4; ++i) acc[i] = fmaf(v, bf16_to_f32(sp[i]), acc[i]);
    }
    float4 o = {acc[0], acc[1], acc[2], acc[3]};
    *reinterpret_cast<float4*>(out + (size_t)node * 64 + f4 * 4) = o;
}

extern "C" void kernel_launch(void* const* d_in, const int* in_sizes, int n_in,
                              void* d_out, int out_size, void* d_ws, size_t ws_size,
                              hipStream_t stream) {
    const float* x    = (const float*)d_in[0];
    const int*   erow = (const int*)d_in[1];
    const int*   ecol = (const int*)d_in[2];
    const float* eval = (const float*)d_in[3];
    const float* W1   = (const float*)d_in[4];
    const float* b1   = (const float*)d_in[5];
    const float* W2   = (const float*)d_in[6];
    const float* b2   = (const float*)d_in[7];
    const float* W3   = (const float*)d_in[8];
    const float* b3   = (const float*)d_in[9];
    float* out = (float*)d_out;

    const size_t nf = (size_t)N_NODES * 128;
    unsigned short* Xb  = (unsigned short*)d_ws;
    unsigned short* Ab  = Xb + nf;
    unsigned short* Wt1 = Ab + nf;
    unsigned short* Wt2 = Wt1 + 128 * 128;
    unsigned short* Wt3 = Wt2 + 128 * 128;
    int*   cnt    = (int*)(Wt3 + 64 * 128);              // N_NODES * CNT_STRIDE
    int*   rank   = cnt + (size_t)N_NODES * CNT_STRIDE;  // N_EDGES
    int*   rptr   = rank + N_EDGES;                      // N_NODES + 1
    unsigned int* cpack = (unsigned int*)(rptr + N_NODES + 1);  // N_EDGES
    int*   slocal = (int*)(cpack + N_EDGES);             // N_NODES
    int*   stsum  = slocal + N_NODES;                    // tiles

    const int blk = 256;
    const int ntiles_g = (N_NODES + 63) / 64;
    const int gemm_grid = 256;
    const int agg_grid = (int)(((long long)N_NODES * 16 + blk - 1) / blk);
    const int ntiles = (N_NODES + SCAN_TILE - 1) / SCAN_TILE;

    // ---- fused prep (x->bf16, W transposes, cnt zero)
    {
        long long total = XN4 + W128 + W128 + W64 + CNT4;
        prep<<<(int)((total + blk - 1) / blk), blk, 0, stream>>>(
            x, Xb, W1, W2, W3, Wt1, Wt2, Wt3, cnt);
    }
    rank_histogram<<<(N_EDGES + blk - 1) / blk, blk, 0, stream>>>(erow, cnt, rank);
    scan_tiles<<<ntiles, 256, 0, stream>>>(cnt, slocal, stsum, N_NODES);
    scan_finalize<<<ntiles, 256, 0, stream>>>(slocal, stsum, ntiles, rptr, N_NODES);
    fill_csr<<<(N_EDGES + blk - 1) / blk, blk, 0, stream>>>(erow, ecol, eval, rptr,
                                                            rank, cpack);

    // ---- Layer 1
    gemm_mfma<128, true><<<gemm_grid, 256, 0, stream>>>(Xb, Wt1, Ab, N_NODES, ntiles_g);
    aggregate_bf16<<<agg_grid, blk, 0, stream>>>(Ab, rptr, cpack, b1, Xb, N_NODES);

    // ---- Layer 2
    gemm_mfma<128, true><<<gemm_grid, 256, 0, stream>>>(Xb, Wt2, Ab, N_NODES, ntiles_g);
    aggregate_bf16<<<agg_grid, blk, 0, stream>>>(Ab, rptr, cpack, b2, Xb, N_NODES);

    // ---- Layer 3 (bf16 support, fp32 accumulate + fp32 out)
    gemm_mfma<64, true><<<gemm_grid, 256, 0, stream>>>(Xb, Wt3, Ab, N_NODES, ntiles_g);
    aggregate_bf16_64<<<agg_grid, blk, 0, stream>>>(Ab, rptr, cpack, b3, out, N_NODES);
}

// Round 10
// 262.819 us; speedup vs baseline: 1.0834x; 1.0326x over previous
//
#include <hip/hip_runtime.h>

#define N_NODES 50000
#define N_EDGES 800000
#define SCAN_TILE 2048  // 256 threads x 8 elems
#define CNT_STRIDE 16   // one counter per 64B line (kills false sharing)
#define GEMM_BLOCKS 256

static_assert(N_NODES < 65536, "col must fit in 16 bits for packed CSR");

typedef __attribute__((ext_vector_type(4))) float f32x4;
typedef __attribute__((ext_vector_type(8))) short bf16x8;

__device__ inline unsigned short f32_to_bf16(float f) {
    unsigned int u = __builtin_bit_cast(unsigned int, f);
    u += 0x7FFF + ((u >> 16) & 1);  // RNE
    return (unsigned short)(u >> 16);
}
__device__ inline float bf16_to_f32(unsigned short h) {
    unsigned int u = ((unsigned int)h) << 16;
    return __builtin_bit_cast(float, u);
}

// ---------------------------------------------------------------------------
// Fused prep: W1/W2/W3 -> transposed bf16, zero cnt (x conversion moved into
// layer-1 GEMM staging). cnt[1] doubles as the scan done-flag (never touched
// by histogram/scan, which only use indices node*CNT_STRIDE).
// ---------------------------------------------------------------------------
#define W128  (128 * 128)
#define W64   (128 * 64)
#define CNT4  (N_NODES * CNT_STRIDE / 4)       // 200,000 int4s

__global__ void prep(const float* __restrict__ W1, const float* __restrict__ W2,
                     const float* __restrict__ W3, unsigned short* __restrict__ Wt1,
                     unsigned short* __restrict__ Wt2, unsigned short* __restrict__ Wt3,
                     int* __restrict__ cnt) {
    long long gid = (long long)blockIdx.x * blockDim.x + threadIdx.x;
    long long r = gid;
    if (r < W128) {
        int k = (int)r / 128, m = (int)r % 128;
        Wt1[m * 128 + k] = f32_to_bf16(W1[r]);
        return;
    }
    r -= W128;
    if (r < W128) {
        int k = (int)r / 128, m = (int)r % 128;
        Wt2[m * 128 + k] = f32_to_bf16(W2[r]);
        return;
    }
    r -= W128;
    if (r < W64) {
        int k = (int)r / 64, m = (int)r % 64;
        Wt3[m * 128 + k] = f32_to_bf16(W3[r]);
        return;
    }
    r -= W64;
    if (r < CNT4) {
        int4 z = {0, 0, 0, 0};
        reinterpret_cast<int4*>(cnt)[r] = z;
    }
}

// ---------------------------------------------------------------------------
// CSR build: rank histogram (one atomic pass, rank returned) -> single-dispatch
// scan (spin on tile-done counter; 25 blocks always co-resident) ->
// atomic-free slot fill (merged into the layer-1 GEMM dispatch below).
// ---------------------------------------------------------------------------
__global__ void rank_histogram(const int* __restrict__ erow, int* __restrict__ cnt,
                               int* __restrict__ rank) {
    int e = blockIdx.x * blockDim.x + threadIdx.x;
    if (e < N_EDGES) rank[e] = atomicAdd(&cnt[(size_t)erow[e] * CNT_STRIDE], 1);
}

// One dispatch: per-tile scan -> publish tile total -> spin until all tiles
// published -> add global offset -> emit rptr. done = &cnt[1] (zeroed in prep).
__global__ void scan_fused(const int* __restrict__ cnt, int* __restrict__ tsum,
                           int* __restrict__ done, int* __restrict__ rptr,
                           int n, int ntiles) {
    __shared__ int sums[256];
    __shared__ int off_s;
    const int t = threadIdx.x;
    const int b = blockIdx.x;
    const int base = b * SCAN_TILE + t * 8;
    int v[8], pref[8];
    int s = 0;
#pragma unroll
    for (int i = 0; i < 8; ++i) {
        v[i] = (base + i < n) ? cnt[(size_t)(base + i) * CNT_STRIDE] : 0;
        s += v[i];
    }
    sums[t] = s;
    __syncthreads();
    for (int off = 1; off < 256; off <<= 1) {
        int x = (t >= off) ? sums[t - off] : 0;
        __syncthreads();
        sums[t] += x;
        __syncthreads();
    }
    int run = sums[t] - s;  // exclusive prefix of this thread within tile
#pragma unroll
    for (int i = 0; i < 8; ++i) {
        pref[i] = run;
        run += v[i];
    }
    if (t == 255) {
        tsum[b] = run;  // tile total (inclusive)
        __threadfence();
        atomicAdd(done, 1);
    }
    if (t == 0) {
        while (__hip_atomic_load(done, __ATOMIC_ACQUIRE, __HIP_MEMORY_SCOPE_AGENT) <
               ntiles) {
        }
        __threadfence();
        int off = 0;
        for (int i = 0; i < b; ++i) off += tsum[i];
        off_s = off;
        if (b == 0) {
            int tot = 0;
            for (int i = 0; i < ntiles; ++i) tot += tsum[i];
            rptr[n] = tot;
        }
    }
    __syncthreads();
    const int off = off_s;
#pragma unroll
    for (int i = 0; i < 8; ++i) {
        int idx = base + i;
        if (idx < n) rptr[idx] = pref[i] + off;
    }
}

// ---------------------------------------------------------------------------
// MFMA GEMM body (persistent-W, grid-stride over 64-row tiles).
// IN_F32: stage fp32 source, converting to bf16 on the fly (layer 1).
// Fragment layouts [measured m89/m91/m120].
// ---------------------------------------------------------------------------
template <int NOUT, bool OUT_BF16, bool IN_F32>
__device__ __forceinline__ void gemm_body(
    const void* __restrict__ Xin, const unsigned short* __restrict__ Wt,
    void* __restrict__ Yv, int N, int ntiles, int bid, int nblocks,
    unsigned short* Xs, unsigned short* Ws) {
    constexpr int K = 128;
    constexpr int KP = K + 8;
    constexpr int NT = NOUT / 16;

    const int tid = threadIdx.x;
    const int wave = tid >> 6;
    const int lane = tid & 63;
    const int m = lane & 15;
    const int quad = lane >> 4;
    const int rowbase = wave * 16;

    for (int idx = tid; idx < NOUT * 16; idx += 256) {
        int r = idx >> 4, ch = idx & 15;
        uint4 v = *reinterpret_cast<const uint4*>(Wt + r * K + ch * 8);
        *reinterpret_cast<uint4*>(Ws + r * KP + ch * 8) = v;
    }

    for (int tile = bid; tile < ntiles; tile += nblocks) {
        const int block_row = tile * 64;
        if (IN_F32) {
            const float* xf = (const float*)Xin;
            for (int idx = tid; idx < 64 * 16; idx += 256) {
                int r = idx >> 4, ch = idx & 15;
                int gr = block_row + r;
                if (gr >= N) gr = N - 1;
                const float4* xp =
                    reinterpret_cast<const float4*>(xf + (size_t)gr * K + ch * 8);
                float4 a = xp[0], b = xp[1];
                uint4 o;
                o.x = (unsigned int)f32_to_bf16(a.x) | ((unsigned int)f32_to_bf16(a.y) << 16);
                o.y = (unsigned int)f32_to_bf16(a.z) | ((unsigned int)f32_to_bf16(a.w) << 16);
                o.z = (unsigned int)f32_to_bf16(b.x) | ((unsigned int)f32_to_bf16(b.y) << 16);
                o.w = (unsigned int)f32_to_bf16(b.z) | ((unsigned int)f32_to_bf16(b.w) << 16);
                *reinterpret_cast<uint4*>(Xs + r * KP + ch * 8) = o;
            }
        } else {
            const unsigned short* xb = (const unsigned short*)Xin;
            for (int idx = tid; idx < 64 * 16; idx += 256) {
                int r = idx >> 4, ch = idx & 15;
                int gr = block_row + r;
                if (gr >= N) gr = N - 1;
                uint4 v = *reinterpret_cast<const uint4*>(xb + (size_t)gr * K + ch * 8);
                *reinterpret_cast<uint4*>(Xs + r * KP + ch * 8) = v;
            }
        }
        __syncthreads();

        f32x4 acc[NT];
#pragma unroll
        for (int t = 0; t < NT; ++t) acc[t] = (f32x4){0.f, 0.f, 0.f, 0.f};

#pragma unroll
        for (int kt = 0; kt < 4; ++kt) {
            bf16x8 a = *reinterpret_cast<const bf16x8*>(
                Xs + (rowbase + m) * KP + kt * 32 + quad * 8);
#pragma unroll
            for (int t = 0; t < NT; ++t) {
                bf16x8 b = *reinterpret_cast<const bf16x8*>(
                    Ws + (t * 16 + m) * KP + kt * 32 + quad * 8);
                acc[t] = __builtin_amdgcn_mfma_f32_16x16x32_bf16(a, b, acc[t], 0, 0, 0);
            }
        }
        __syncthreads();

#pragma unroll
        for (int t = 0; t < NT; ++t) {
#pragma unroll
            for (int r = 0; r < 4; ++r) {
                int grow = block_row + rowbase + quad * 4 + r;
                if (grow < N) {
                    if (OUT_BF16)
                        reinterpret_cast<unsigned short*>(Yv)[(size_t)grow * NOUT + t * 16 + m] =
                            f32_to_bf16(acc[t][r]);
                    else
                        reinterpret_cast<float*>(Yv)[(size_t)grow * NOUT + t * 16 + m] = acc[t][r];
                }
            }
        }
    }
}

// Layers 2/3: plain GEMM kernel (bf16 input).
template <int NOUT, bool OUT_BF16>
__global__ __launch_bounds__(256) void gemm_mfma(
    const unsigned short* __restrict__ Xb, const unsigned short* __restrict__ Wt,
    void* __restrict__ Yv, int N, int ntiles) {
    constexpr int KP = 128 + 8;
    __shared__ unsigned short Xs[64 * KP];
    __shared__ unsigned short Ws[NOUT * KP];
    gemm_body<NOUT, OUT_BF16, false>(Xb, Wt, Yv, N, ntiles, blockIdx.x, gridDim.x,
                                     Xs, Ws);
}

// Layer 1 merged with atomic-free CSR fill: blocks [0, GEMM_BLOCKS) run the
// persistent GEMM (fp32 input); blocks >= GEMM_BLOCKS fill cpack (independent
// work — scatter-store-bound, backfills CU slots around the GEMM).
__global__ __launch_bounds__(256) void gemm1_fill(
    const float* __restrict__ x, const unsigned short* __restrict__ Wt,
    unsigned short* __restrict__ Yb, int N, int ntiles,
    const int* __restrict__ erow, const int* __restrict__ ecol,
    const float* __restrict__ eval, const int* __restrict__ rptr,
    const int* __restrict__ rank, unsigned int* __restrict__ cpack) {
    constexpr int KP = 128 + 8;
    __shared__ unsigned short Xs[64 * KP];
    __shared__ unsigned short Ws[128 * KP];
    if (blockIdx.x < GEMM_BLOCKS) {
        gemm_body<128, true, true>(x, Wt, Yb, N, ntiles, blockIdx.x, GEMM_BLOCKS,
                                   Xs, Ws);
    } else {
        int e = (blockIdx.x - GEMM_BLOCKS) * blockDim.x + threadIdx.x;
        if (e < N_EDGES) {
            int slot = rptr[erow[e]] + rank[e];
            unsigned int p = (unsigned int)(ecol[e] & 0xFFFF) |
                             ((unsigned int)f32_to_bf16(eval[e]) << 16);
            cpack[slot] = p;
        }
    }
}

// ---------------------------------------------------------------------------
// CSR aggregation, bf16 source [N,128], fused bias+ReLU, bf16 out.
// 16 lanes/node, 8 features/lane. Tiered unroll 8/4/2/1 (proven round 9).
// ---------------------------------------------------------------------------
__global__ void aggregate_bf16(const unsigned short* __restrict__ S,
                               const int* __restrict__ rptr,
                               const unsigned int* __restrict__ cpack,
                               const float* __restrict__ bias,
                               unsigned short* __restrict__ outb, int N) {
    const int node = blockIdx.x * (blockDim.x / 16) + threadIdx.x / 16;
    const int f8 = threadIdx.x & 15;
    if (node >= N) return;
    const int beg = rptr[node];
    const int end = rptr[node + 1];
    float acc[8];
#pragma unroll
    for (int i = 0; i < 8; ++i) acc[i] = bias[f8 * 8 + i];
    int j = beg;
    for (; j + 8 <= end; j += 8) {
        unsigned int p[8];
        uint4 s[8];
#pragma unroll
        for (int u = 0; u < 8; ++u) p[u] = cpack[j + u];
#pragma unroll
        for (int u = 0; u < 8; ++u)
            s[u] = *reinterpret_cast<const uint4*>(S + (size_t)(p[u] & 0xFFFF) * 128 + f8 * 8);
#pragma unroll
        for (int u = 0; u < 8; ++u) {
            const float v = bf16_to_f32((unsigned short)(p[u] >> 16));
            const unsigned short* sp = reinterpret_cast<const unsigned short*>(&s[u]);
#pragma unroll
            for (int i = 0; i < 8; ++i) acc[i] = fmaf(v, bf16_to_f32(sp[i]), acc[i]);
        }
    }
    if (j + 4 <= end) {
        unsigned int p[4];
        uint4 s[4];
#pragma unroll
        for (int u = 0; u < 4; ++u) p[u] = cpack[j + u];
#pragma unroll
        for (int u = 0; u < 4; ++u)
            s[u] = *reinterpret_cast<const uint4*>(S + (size_t)(p[u] & 0xFFFF) * 128 + f8 * 8);
#pragma unroll
        for (int u = 0; u < 4; ++u) {
            const float v = bf16_to_f32((unsigned short)(p[u] >> 16));
            const unsigned short* sp = reinterpret_cast<const unsigned short*>(&s[u]);
#pragma unroll
            for (int i = 0; i < 8; ++i) acc[i] = fmaf(v, bf16_to_f32(sp[i]), acc[i]);
        }
        j += 4;
    }
    if (j + 2 <= end) {
        unsigned int p[2];
        uint4 s[2];
#pragma unroll
        for (int u = 0; u < 2; ++u) p[u] = cpack[j + u];
#pragma unroll
        for (int u = 0; u < 2; ++u)
            s[u] = *reinterpret_cast<const uint4*>(S + (size_t)(p[u] & 0xFFFF) * 128 + f8 * 8);
#pragma unroll
        for (int u = 0; u < 2; ++u) {
            const float v = bf16_to_f32((unsigned short)(p[u] >> 16));
            const unsigned short* sp = reinterpret_cast<const unsigned short*>(&s[u]);
#pragma unroll
            for (int i = 0; i < 8; ++i) acc[i] = fmaf(v, bf16_to_f32(sp[i]), acc[i]);
        }
        j += 2;
    }
    if (j < end) {
        unsigned int p = cpack[j];
        uint4 s = *reinterpret_cast<const uint4*>(S + (size_t)(p & 0xFFFF) * 128 + f8 * 8);
        const float v = bf16_to_f32((unsigned short)(p >> 16));
        const unsigned short* sp = reinterpret_cast<const unsigned short*>(&s);
#pragma unroll
        for (int i = 0; i < 8; ++i) acc[i] = fmaf(v, bf16_to_f32(sp[i]), acc[i]);
    }
    unsigned short o[8];
#pragma unroll
    for (int i = 0; i < 8; ++i) o[i] = f32_to_bf16(fmaxf(acc[i], 0.0f));
    *reinterpret_cast<uint4*>(outb + (size_t)node * 128 + f8 * 8) =
        *reinterpret_cast<uint4*>(o);
}

// ---------------------------------------------------------------------------
// Layer-3 aggregation: bf16 source [N,64], + bias, no activation, fp32 out.
// ---------------------------------------------------------------------------
__global__ void aggregate_bf16_64(const unsigned short* __restrict__ S,
                                  const int* __restrict__ rptr,
                                  const unsigned int* __restrict__ cpack,
                                  const float* __restrict__ bias,
                                  float* __restrict__ out, int N) {
    const int node = blockIdx.x * (blockDim.x / 16) + threadIdx.x / 16;
    const int f4 = threadIdx.x & 15;
    if (node >= N) return;
    const int beg = rptr[node];
    const int end = rptr[node + 1];
    float acc[4];
#pragma unroll
    for (int i = 0; i < 4; ++i) acc[i] = bias[f4 * 4 + i];
    int j = beg;
    for (; j + 8 <= end; j += 8) {
        unsigned int p[8];
        uint2 s[8];
#pragma unroll
        for (int u = 0; u < 8; ++u) p[u] = cpack[j + u];
#pragma unroll
        for (int u = 0; u < 8; ++u)
            s[u] = *reinterpret_cast<const uint2*>(S + (size_t)(p[u] & 0xFFFF) * 64 + f4 * 4);
#pragma unroll
        for (int u = 0; u < 8; ++u) {
            const float v = bf16_to_f32((unsigned short)(p[u] >> 16));
            const unsigned short* sp = reinterpret_cast<const unsigned short*>(&s[u]);
#pragma unroll
            for (int i = 0; i < 4; ++i) acc[i] = fmaf(v, bf16_to_f32(sp[i]), acc[i]);
        }
    }
    if (j + 4 <= end) {
        unsigned int p[4];
        uint2 s[4];
#pragma unroll
        for (int u = 0; u < 4; ++u) p[u] = cpack[j + u];
#pragma unroll
        for (int u = 0; u < 4; ++u)
            s[u] = *reinterpret_cast<const uint2*>(S + (size_t)(p[u] & 0xFFFF) * 64 + f4 * 4);
#pragma unroll
        for (int u = 0; u < 4; ++u) {
            const float v = bf16_to_f32((unsigned short)(p[u] >> 16));
            const unsigned short* sp = reinterpret_cast<const unsigned short*>(&s[u]);
#pragma unroll
            for (int i = 0; i < 4; ++i) acc[i] = fmaf(v, bf16_to_f32(sp[i]), acc[i]);
        }
        j += 4;
    }
    if (j + 2 <= end) {
        unsigned int p[2];
        uint2 s[2];
#pragma unroll
        for (int u = 0; u < 2; ++u) p[u] = cpack[j + u];
#pragma unroll
        for (int u = 0; u < 2; ++u)
            s[u] = *reinterpret_cast<const uint2*>(S + (size_t)(p[u] & 0xFFFF) * 64 + f4 * 4);
#pragma unroll
        for (int u = 0; u < 2; ++u) {
            const float v = bf16_to_f32((unsigned short)(p[u] >> 16));
            const unsigned short* sp = reinterpret_cast<const unsigned short*>(&s[u]);
#pragma unroll
            for (int i = 0; i < 4; ++i) acc[i] = fmaf(v, bf16_to_f32(sp[i]), acc[i]);
        }
        j += 2;
    }
    if (j < end) {
        unsigned int p = cpack[j];
        uint2 s = *reinterpret_cast<const uint2*>(S + (size_t)(p & 0xFFFF) * 64 + f4 * 4);
        const float v = bf16_to_f32((unsigned short)(p >> 16));
        const unsigned short* sp = reinterpret_cast<const unsigned short*>(&s);
#pragma unroll
        for (int i = 0; i < 4; ++i) acc[i] = fmaf(v, bf16_to_f32(sp[i]), acc[i]);
    }
    float4 o = {acc[0], acc[1], acc[2], acc[3]};
    *reinterpret_cast<float4*>(out + (size_t)node * 64 + f4 * 4) = o;
}

extern "C" void kernel_launch(void* const* d_in, const int* in_sizes, int n_in,
                              void* d_out, int out_size, void* d_ws, size_t ws_size,
                              hipStream_t stream) {
    const float* x    = (const float*)d_in[0];
    const int*   erow = (const int*)d_in[1];
    const int*   ecol = (const int*)d_in[2];
    const float* eval = (const float*)d_in[3];
    const float* W1   = (const float*)d_in[4];
    const float* b1   = (const float*)d_in[5];
    const float* W2   = (const float*)d_in[6];
    const float* b2   = (const float*)d_in[7];
    const float* W3   = (const float*)d_in[8];
    const float* b3   = (const float*)d_in[9];
    float* out = (float*)d_out;

    const size_t nf = (size_t)N_NODES * 128;
    unsigned short* Xb  = (unsigned short*)d_ws;     // inter-layer H (bf16)
    unsigned short* Ab  = Xb + nf;                   // support buffer (bf16)
    unsigned short* Wt1 = Ab + nf;
    unsigned short* Wt2 = Wt1 + 128 * 128;
    unsigned short* Wt3 = Wt2 + 128 * 128;
    int*   cnt    = (int*)(Wt3 + 64 * 128);              // N_NODES * CNT_STRIDE
    int*   rank   = cnt + (size_t)N_NODES * CNT_STRIDE;  // N_EDGES
    int*   rptr   = rank + N_EDGES;                      // N_NODES + 1
    unsigned int* cpack = (unsigned int*)(rptr + N_NODES + 1);  // N_EDGES
    int*   stsum  = (int*)(cpack + N_EDGES);             // tiles
    int*   done   = cnt + 1;  // unused cnt slot (only node*CNT_STRIDE touched)

    const int blk = 256;
    const int ntiles_g = (N_NODES + 63) / 64;
    const int agg_grid = (int)(((long long)N_NODES * 16 + blk - 1) / blk);
    const int ntiles = (N_NODES + SCAN_TILE - 1) / SCAN_TILE;
    const int fill_blocks = (N_EDGES + blk - 1) / blk;

    // ---- prep (W transposes + cnt/done zero)
    {
        long long total = W128 + W128 + W64 + CNT4;
        prep<<<(int)((total + blk - 1) / blk), blk, 0, stream>>>(
            W1, W2, W3, Wt1, Wt2, Wt3, cnt);
    }
    rank_histogram<<<(N_EDGES + blk - 1) / blk, blk, 0, stream>>>(erow, cnt, rank);
    scan_fused<<<ntiles, 256, 0, stream>>>(cnt, stsum, done, rptr, N_NODES, ntiles);

    // ---- Layer 1 GEMM (fp32 x input) merged with CSR fill
    gemm1_fill<<<GEMM_BLOCKS + fill_blocks, 256, 0, stream>>>(
        x, Wt1, Ab, N_NODES, ntiles_g, erow, ecol, eval, rptr, rank, cpack);
    aggregate_bf16<<<agg_grid, blk, 0, stream>>>(Ab, rptr, cpack, b1, Xb, N_NODES);

    // ---- Layer 2
    gemm_mfma<128, true><<<GEMM_BLOCKS, 256, 0, stream>>>(Xb, Wt2, Ab, N_NODES, ntiles_g);
    aggregate_bf16<<<agg_grid, blk, 0, stream>>>(Ab, rptr, cpack, b2, Xb, N_NODES);

    // ---- Layer 3 (bf16 support, fp32 accumulate + fp32 out)
    gemm_mfma<64, true><<<GEMM_BLOCKS, 256, 0, stream>>>(Xb, Wt3, Ab, N_NODES, ntiles_g);
    aggregate_bf16_64<<<agg_grid, blk, 0, stream>>>(Ab, rptr, cpack, b3, out, N_NODES);
}